// Round 12
// baseline (1190.800 us; speedup 1.0000x reference)
//
#include <hip/hip_runtime.h>
#include <hip/hip_bf16.h>
#include <hip/hip_cooperative_groups.h>

namespace cg = cooperative_groups;

__device__ __forceinline__ float lrelu02(float v) { return v > 0.f ? v : 0.2f * v; }

// manual bf16 <-> f32 (RNE); finite data only
__device__ __forceinline__ float bf2f(unsigned short u) {
    union { unsigned int i; float f; } v; v.i = ((unsigned int)u) << 16; return v.f;
}
__device__ __forceinline__ unsigned short f2bf(float f) {
    union { float f; unsigned int i; } v; v.f = f;
    unsigned int x = v.i;
    return (unsigned short)((x + 0x7fffu + ((x >> 16) & 1u)) >> 16);
}
// fp16 store helper (RNE)
__device__ __forceinline__ unsigned short f2h(float f) {
    union { _Float16 h; unsigned short u; } v; v.h = (_Float16)f; return v.u;
}

typedef float f32x4 __attribute__((ext_vector_type(4)));
typedef short s16x8 __attribute__((ext_vector_type(8)));

// half2 vector type derived from the builtin itself (r10 compile fix)
using half2v = decltype(__builtin_amdgcn_cvt_pkrtz(0.f, 0.f));

__device__ __forceinline__ half2v u2h2(unsigned int u) {
    union { unsigned int u; half2v h; } v; v.u = u; return v.h;
}
__device__ __forceinline__ unsigned int h22u(half2v h) {
    union { unsigned int u; half2v h; } v; v.h = h; return v.u;
}

// ---------- single cooperative kernel: the ENTIRE CSR build ----------
// r11 ledger: CSR chain was 6 serialized dispatches (memset, rank, blocksum, scanbsum,
// rowptr, place), each a full device drain for small work; blob (incl. gat2/place/scans/
// overhead) ~205us with nothing individually visible. Collapse into ONE cooperative
// kernel with grid.sync() phase barriers: zero -> rank(atomic) -> segsums -> scan ->
// rowptr -> place. 1024 blocks x 256 thr (4 waves/block, co-resident cap 2048 at <=64
// VGPR). threadfence before sync for cross-XCD visibility (G16). Next round its top-5
// entry exposes the true atomic+scatter cost.
__global__ __launch_bounds__(256) void csr_build_k(
    const int* __restrict__ ei, int E, int N,
    int* __restrict__ deg, int* __restrict__ rank,
    int* __restrict__ bsum, int* __restrict__ rowptr, int* __restrict__ csr)
{
    cg::grid_group grid = cg::this_grid();
    const int tid = blockIdx.x * 256 + threadIdx.x;
    const int gstride = gridDim.x * 256;
    const int total = E + N;
    __shared__ int sh[256];
    __shared__ int carry;

    // phase 0: zero deg
    for (int i = tid; i < N; i += gstride) deg[i] = 0;
    __threadfence();
    grid.sync();

    // phase 1: histogram + rank (atomicAdd with return; device scope)
    for (int e = tid; e < total; e += gstride) {
        int d = (e < E) ? ei[E + e] : (e - E);
        rank[e] = atomicAdd(&deg[d], 1);
    }
    __threadfence();
    grid.sync();

    // phase 2: per-256-segment sums
    const int nseg = (N + 255) / 256;
    for (int seg = blockIdx.x; seg < nseg; seg += gridDim.x) {
        int i = seg * 256 + threadIdx.x;
        sh[threadIdx.x] = (i < N) ? deg[i] : 0;
        __syncthreads();
        for (int off = 128; off; off >>= 1) {
            if (threadIdx.x < off) sh[threadIdx.x] += sh[threadIdx.x + off];
            __syncthreads();
        }
        if (threadIdx.x == 0) bsum[seg] = sh[0];
        __syncthreads();
    }
    __threadfence();
    grid.sync();

    // phase 3: exclusive scan of bsum (block 0 only; nseg ~391)
    if (blockIdx.x == 0) {
        if (threadIdx.x == 0) carry = 0;
        __syncthreads();
        for (int base = 0; base < nseg; base += 256) {
            int i = base + threadIdx.x;
            int v = (i < nseg) ? bsum[i] : 0;
            sh[threadIdx.x] = v;
            __syncthreads();
            for (int off = 1; off < 256; off <<= 1) {
                int t = (threadIdx.x >= off) ? sh[threadIdx.x - off] : 0;
                __syncthreads();
                sh[threadIdx.x] += t;
                __syncthreads();
            }
            if (i < nseg) bsum[i] = sh[threadIdx.x] - v + carry;   // exclusive
            __syncthreads();
            if (threadIdx.x == 0) carry += sh[255];
            __syncthreads();
        }
    }
    __threadfence();
    grid.sync();

    // phase 4: rowptr = bsum[seg] + intra-segment exclusive scan
    for (int seg = blockIdx.x; seg < nseg; seg += gridDim.x) {
        int i = seg * 256 + threadIdx.x;
        int v = (i < N) ? deg[i] : 0;
        sh[threadIdx.x] = v;
        __syncthreads();
        for (int off = 1; off < 256; off <<= 1) {
            int t = (threadIdx.x >= off) ? sh[threadIdx.x - off] : 0;
            __syncthreads();
            sh[threadIdx.x] += t;
            __syncthreads();
        }
        if (i < N) rowptr[i] = bsum[seg] + sh[threadIdx.x] - v;
        __syncthreads();
    }
    if (tid == 0) rowptr[N] = total;
    __threadfence();
    grid.sync();

    // phase 5: place (pure scatter, rank known)
    for (int e = tid; e < total; e += gstride) {
        int s, d;
        if (e < E) { s = ei[e]; d = ei[E + e]; } else { s = d = e - E; }
        csr[rowptr[d] + rank[e]] = s;
    }
}

// ---------- layer-1 dense via MFMA ----------
// (r5: MFMA verified, absmax held; fp16 h1 output for gat1's fdot2 path.)
__global__ __launch_bounds__(512) void gemm1_k(
    const float* __restrict__ x, const float* __restrict__ W1,
    const float* __restrict__ aw_s, const float* __restrict__ aw_d,
    unsigned short* __restrict__ h1b, float* __restrict__ as1, float* __restrict__ ad1, int N)
{
    // --- stage W1 transposed as bf16: Wt[col][k ^ ((col&7)<<3)] ---
    __shared__ unsigned short Wt[128 * 128];   // 32 KB
    {
        const float4* W4 = (const float4*)W1;
        for (int i = threadIdx.x; i < 128 * 32; i += 512) {
            float4 f = W4[i];                      // row k = i>>5, cols 4t..4t+3
            int k = i >> 5, c4 = (i & 31) * 4;
            #pragma unroll
            for (int j = 0; j < 4; ++j) {
                int col = c4 + j;
                float fv = j == 0 ? f.x : j == 1 ? f.y : j == 2 ? f.z : f.w;
                Wt[col * 128 + (k ^ ((col & 7) << 3))] = f2bf(fv);
            }
        }
    }

    const int lane = threadIdx.x & 63;
    const int wv   = threadIdx.x >> 6;          // 0..7
    const int li   = lane & 15;                 // M-row (A) / N-col (B,D) index
    const int kg   = lane >> 4;                 // k-subchunk 0..3
    const int row0 = blockIdx.x * 128 + wv * 16;

    const int rc = (row0 + li < N) ? (row0 + li) : (N - 1);   // clamped A row
    const float4* xr = (const float4*)(x + (size_t)rc * 128);

    f32x4 acc[8];
    #pragma unroll
    for (int ct = 0; ct < 8; ++ct) acc[ct] = {0.f, 0.f, 0.f, 0.f};

    __syncthreads();

    #pragma unroll
    for (int ks = 0; ks < 4; ++ks) {
        // A fragment: x[rc][ks*32 + kg*8 .. +7] as hi/lo bf16 split
        float4 f0 = xr[ks * 8 + kg * 2];
        float4 f1 = xr[ks * 8 + kg * 2 + 1];
        float xf[8] = {f0.x, f0.y, f0.z, f0.w, f1.x, f1.y, f1.z, f1.w};
        s16x8 ahi, alo;
        #pragma unroll
        for (int j = 0; j < 8; ++j) {
            unsigned short h = f2bf(xf[j]);
            ahi[j] = (short)h;
            alo[j] = (short)f2bf(xf[j] - bf2f(h));
        }
        const int kbase = ks * 32 + kg * 8;
        #pragma unroll
        for (int ct = 0; ct < 8; ++ct) {
            const int col = ct * 16 + li;
            const s16x8 b = *reinterpret_cast<const s16x8*>(
                Wt + col * 128 + (kbase ^ ((col & 7) << 3)));
            acc[ct] = __builtin_amdgcn_mfma_f32_16x16x32_bf16(ahi, b, acc[ct], 0, 0, 0);
            acc[ct] = __builtin_amdgcn_mfma_f32_16x16x32_bf16(alo, b, acc[ct], 0, 0, 0);
        }
    }

    // --- epilogue: attn dots + fp16 h1 write ---
    float aws_[8], awd_[8];
    #pragma unroll
    for (int t = 0; t < 8; ++t) { aws_[t] = aw_s[t * 16 + li]; awd_[t] = aw_d[t * 16 + li]; }

    #pragma unroll
    for (int i = 0; i < 4; ++i) {
        const int gr = row0 + (lane >> 4) * 4 + i;
        const bool valid = gr < N;
        float s0 = acc[0][i] * aws_[0] + acc[1][i] * aws_[1];
        float s1 = acc[2][i] * aws_[2] + acc[3][i] * aws_[3];
        float s2 = acc[4][i] * aws_[4] + acc[5][i] * aws_[5];
        float s3 = acc[6][i] * aws_[6] + acc[7][i] * aws_[7];
        float d0 = acc[0][i] * awd_[0] + acc[1][i] * awd_[1];
        float d1 = acc[2][i] * awd_[2] + acc[3][i] * awd_[3];
        float d2 = acc[4][i] * awd_[4] + acc[5][i] * awd_[5];
        float d3 = acc[6][i] * awd_[6] + acc[7][i] * awd_[7];
        #pragma unroll
        for (int m = 1; m < 16; m <<= 1) {
            s0 += __shfl_xor(s0, m, 16); s1 += __shfl_xor(s1, m, 16);
            s2 += __shfl_xor(s2, m, 16); s3 += __shfl_xor(s3, m, 16);
            d0 += __shfl_xor(d0, m, 16); d1 += __shfl_xor(d1, m, 16);
            d2 += __shfl_xor(d2, m, 16); d3 += __shfl_xor(d3, m, 16);
        }
        if (valid) {
            if (li < 4) {
                float sv = li == 0 ? s0 : li == 1 ? s1 : li == 2 ? s2 : s3;
                float dv = li == 0 ? d0 : li == 1 ? d1 : li == 2 ? d2 : d3;
                as1[gr * 4 + li] = sv;
                ad1[gr * 4 + li] = dv;
            }
            #pragma unroll
            for (int ct = 0; ct < 8; ++ct)
                h1b[(size_t)gr * 128 + ct * 16 + li] = f2h(acc[ct][i]);
        }
    }
}

// ---------- layer-1 fused: softmax-aggregate + bias + ELU + gemm2 + attn2 dots ----------
// (r11: fdot2-pair version verified, 114 -> 92us, absmax held. Unchanged this round —
// serves as the measured reference point.)
__global__ __launch_bounds__(256) void gat1_k(
    const int* __restrict__ csr, const int* __restrict__ rowptr,
    const float* __restrict__ as1, const float* __restrict__ ad1,
    const unsigned short* __restrict__ h1b, const float* __restrict__ b1,
    const float* __restrict__ W2, const float* __restrict__ aw_s2, const float* __restrict__ aw_d2,
    float* __restrict__ g, float* __restrict__ as2, float* __restrict__ ad2, int N)
{
    __shared__ float red[4][8][12];   // [wave][src-lane][j]
    const int wv   = threadIdx.x >> 6;
    const int wid  = (blockIdx.x * 256 + threadIdx.x) >> 6;
    const int lane = threadIdx.x & 63;
    if (wid >= N) return;
    const int start = rowptr[wid], end = rowptr[wid + 1];
    const int i16 = lane & 15;
    const int hh  = lane >> 4;
    const float adh = ad1[wid * 4 + hh];
    const float mh  = lrelu02(as1[wid * 4 + hh] + adh);   // self-logit offset (den >= 1)
    const unsigned short* hb = h1b + lane * 2;            // this lane's 2 cols (fp16)

    float den = 0.f, acc0 = 0.f, acc1 = 0.f;

    int   s = 0;
    unsigned int wpku = 0;

    auto pair_step = [&](int p) {
        const int se0 = __builtin_amdgcn_readlane(s, 2 * p);
        const int se1 = __builtin_amdgcn_readlane(s, 2 * p + 1);
        const unsigned int wp = (unsigned int)__shfl((int)wpku, 2 * p, 16);
        const unsigned int pv0 = *(const unsigned int*)(hb + (size_t)se0 * 128);
        const unsigned int pv1 = *(const unsigned int*)(hb + (size_t)se1 * 128);
        const unsigned int lo = __builtin_amdgcn_perm(pv1, pv0, 0x05040100u); // (h_e0[c], h_e1[c])
        const unsigned int hi = __builtin_amdgcn_perm(pv1, pv0, 0x07060302u); // (h_e0[c+1], h_e1[c+1])
        acc0 = __builtin_amdgcn_fdot2(u2h2(wp), u2h2(lo), acc0, false);
        acc1 = __builtin_amdgcn_fdot2(u2h2(wp), u2h2(hi), acc1, false);
    };

    int k0 = start;
    int cnt = end - k0; cnt = cnt > 16 ? 16 : cnt;        // first chunk (>=1: self loop)
    s = (i16 < cnt) ? csr[k0 + i16] : wid;
    float w = (i16 < cnt) ? __expf(lrelu02(as1[(size_t)s * 4 + hh] + adh) - mh) : 0.f;

    while (true) {
        // prefetch next chunk's loads before consuming the current one
        const int k1 = k0 + 16;
        int cnt_n = end - k1; cnt_n = cnt_n > 16 ? 16 : cnt_n;   // may be <= 0
        int   s_n = wid;
        float a_n = 0.f;
        if (cnt_n > 0) {
            s_n = (i16 < cnt_n) ? csr[k1 + i16] : wid;
            a_n = as1[(size_t)s_n * 4 + hh];
        }

        den += w;
        // pack (w_i, w_i+1) on even lanes; pairs stay within the 16-lane head group
        const float wn = __shfl_xor(w, 1);
        wpku = h22u(__builtin_amdgcn_cvt_pkrtz(w, wn));

        if (cnt == 16) {
            #pragma unroll
            for (int p = 0; p < 8; ++p) pair_step(p);
        } else {
            const int pairs = (cnt + 1) >> 1;
            for (int p = 0; p < pairs; ++p) pair_step(p);
        }
        if (cnt_n <= 0) break;
        s = s_n;
        w = (i16 < cnt_n) ? __expf(lrelu02(a_n + adh) - mh) : 0.f;
        k0 = k1; cnt = cnt_n;
    }

    den += __shfl_xor(den, 1); den += __shfl_xor(den, 2);
    den += __shfl_xor(den, 4); den += __shfl_xor(den, 8);
    const float rden = 1.f / (den + 1e-16f);
    float v0 = acc0 * rden + b1[lane * 2];
    float v1 = acc1 * rden + b1[lane * 2 + 1];
    v0 = v0 > 0.f ? v0 : expm1f(v0);
    v1 = v1 > 0.f ? v1 : expm1f(v1);

    // --- fused gemm2: g_j = sum_k elu_out[k] * W2[k][j] (k = 2*lane, 2*lane+1) ---
    const float4 a0 = *(const float4*)(W2 + 16 * lane);
    const float4 a1 = *(const float4*)(W2 + 16 * lane + 4);
    const float4 b0 = *(const float4*)(W2 + 16 * lane + 8);
    const float4 b1v = *(const float4*)(W2 + 16 * lane + 12);
    float p[8];
    p[0] = v0 * a0.x + v1 * b0.x;  p[1] = v0 * a0.y + v1 * b0.y;
    p[2] = v0 * a0.z + v1 * b0.z;  p[3] = v0 * a0.w + v1 * b0.w;
    p[4] = v0 * a1.x + v1 * b1v.x; p[5] = v0 * a1.y + v1 * b1v.y;
    p[6] = v0 * a1.z + v1 * b1v.z; p[7] = v0 * a1.w + v1 * b1v.w;
    #pragma unroll
    for (int j = 0; j < 8; ++j) {
        p[j] += __shfl_xor(p[j], 8);
        p[j] += __shfl_xor(p[j], 16);
        p[j] += __shfl_xor(p[j], 32);
    }
    if (lane < 8) {
        #pragma unroll
        for (int j = 0; j < 8; ++j) red[wv][lane][j] = p[j];
    }
    if (lane < 8) {
        float gj = 0.f;
        #pragma unroll
        for (int c = 0; c < 8; ++c) gj += red[wv][c][lane];
        g[(size_t)wid * 8 + lane] = gj;
        float ts = gj * aw_s2[lane], td = gj * aw_d2[lane];
        ts += __shfl_xor(ts, 1); ts += __shfl_xor(ts, 2); ts += __shfl_xor(ts, 4);
        td += __shfl_xor(td, 1); td += __shfl_xor(td, 2); td += __shfl_xor(td, 4);
        if (lane == 0) { as2[wid] = ts; ad2[wid] = td; }
    }
}

// ---------- layer-2 single-pass softmax+aggregate+epilogue: one wave per dst ----------
// r12: 16-edge chunks (was 8): halves loop iterations, doubles independent g-gathers
// per iteration. Lanes i16 compute w for 16 edges; group g (8 lanes) aggregates edges
// {g, g+8} via width-64 shfl broadcasts. den reduce widened to xor 1/2/4/8 (16 distinct
// edge slots); acc reduce unchanged (xor 8/16/32 across the 8 groups).
__global__ __launch_bounds__(256) void gat2_k(
    const int* __restrict__ csr, const int* __restrict__ rowptr,
    const float* __restrict__ as2, const float* __restrict__ ad2,
    const float* __restrict__ g, const float* __restrict__ b2_,
    const float* __restrict__ Wlin, const float* __restrict__ blin,
    float* __restrict__ out, int N)
{
    const int wid  = (blockIdx.x * 256 + threadIdx.x) >> 6;
    const int lane = threadIdx.x & 63;
    if (wid >= N) return;
    const int start = rowptr[wid], end = rowptr[wid + 1];
    const int i16 = lane & 15;
    const int i8  = lane & 7;
    const int grp = lane >> 3;
    const float adh = ad2[wid];
    const float mh  = lrelu02(as2[wid] + adh);
    float den = 0.f, acc = 0.f;

    int k0 = start;
    int cnt = end - k0; cnt = cnt > 16 ? 16 : cnt;
    int   s = (i16 < cnt) ? csr[k0 + i16] : wid;
    float w = (i16 < cnt) ? __expf(lrelu02(as2[s] + adh) - mh) : 0.f;

    while (true) {
        const int k1 = k0 + 16;
        int cnt_n = end - k1; cnt_n = cnt_n > 16 ? 16 : cnt_n;
        int   s_n = wid;
        float a_n = 0.f;
        if (cnt_n > 0) {
            s_n = (i16 < cnt_n) ? csr[k1 + i16] : wid;
            a_n = as2[s_n];
        }

        den += w;
        const int   se0 = __shfl(s, grp);
        const int   se1 = __shfl(s, grp + 8);
        const float we0 = __shfl(w, grp);
        const float we1 = __shfl(w, grp + 8);
        const float gv0 = g[(size_t)se0 * 8 + i8];
        const float gv1 = g[(size_t)se1 * 8 + i8];
        acc = fmaf(we0, gv0, acc);
        acc = fmaf(we1, gv1, acc);

        if (cnt_n <= 0) break;
        s = s_n;
        w = (i16 < cnt_n) ? __expf(lrelu02(a_n + adh) - mh) : 0.f;
        k0 = k1; cnt = cnt_n;
    }

    den += __shfl_xor(den, 1); den += __shfl_xor(den, 2);
    den += __shfl_xor(den, 4); den += __shfl_xor(den, 8);
    acc += __shfl_xor(acc, 8); acc += __shfl_xor(acc, 16); acc += __shfl_xor(acc, 32);
    float v = acc / (den + 1e-16f) + b2_[i8];
    v = v > 0.f ? v : expm1f(v);
    float t = v * Wlin[i8];
    t += __shfl_xor(t, 1); t += __shfl_xor(t, 2); t += __shfl_xor(t, 4);
    if (lane == 0) out[wid] = 1.f / (1.f + __expf(-(t + blin[0])));
}

extern "C" void kernel_launch(void* const* d_in, const int* in_sizes, int n_in,
                              void* d_out, int out_size, void* d_ws, size_t ws_size,
                              hipStream_t stream)
{
    (void)n_in; (void)out_size; (void)ws_size;
    const float* x    = (const float*)d_in[0];
    const int*   ei   = (const int*)d_in[1];
    // d_in[2] = edge_attr, ignored
    const float* W1   = (const float*)d_in[3];
    const float* as1w = (const float*)d_in[4];
    const float* ad1w = (const float*)d_in[5];
    const float* b1   = (const float*)d_in[6];
    const float* W2   = (const float*)d_in[7];
    const float* as2w = (const float*)d_in[8];
    const float* ad2w = (const float*)d_in[9];
    const float* b2v  = (const float*)d_in[10];
    const float* Wlin = (const float*)d_in[11];
    const float* blin = (const float*)d_in[12];

    const int N = in_sizes[0] / 128;
    const int E = in_sizes[1] / 2;
    const int total = E + N;

    // workspace layout
    float* p = (float*)d_ws;
    unsigned short* h1b = (unsigned short*)p; p += (size_t)N * 64;  // N*128 fp16
    float* as1  = p; p += (size_t)N * 4;
    float* ad1  = p; p += (size_t)N * 4;
    float* g    = p; p += (size_t)N * 8;
    float* as2  = p; p += (size_t)N;
    float* ad2  = p; p += (size_t)N;
    int* deg    = (int*)p; p += (size_t)N;
    int* rowptr = (int*)p; p += (size_t)N + 1;
    int* bsum   = (int*)p; p += ((size_t)N + 255) / 256;
    int* rank   = (int*)p; p += (size_t)total;
    int* csr    = (int*)p; p += (size_t)total;

    // layer-1 GEMM first (independent of graph structure)
    gemm1_k<<<(N + 127) / 128, 512, 0, stream>>>(x, W1, as1w, ad1w, h1b, as1, ad1, N);

    // entire CSR build in one cooperative kernel (replaces memset + 5 kernels)
    {
        int* ei_nc = (int*)ei;  // arg array needs addressable lvalues
        void* args[] = { (void*)&ei_nc, (void*)&E, (void*)&N, (void*)&deg,
                         (void*)&rank, (void*)&bsum, (void*)&rowptr, (void*)&csr };
        hipLaunchCooperativeKernel((void*)csr_build_k, dim3(1024), dim3(256),
                                   args, 0, stream);
    }

    // layer 1: softmax + aggregate + bias + ELU + gemm2 + attn2 dots (fdot2 pairs)
    gat1_k<<<(N * 64 + 255) / 256, 256, 0, stream>>>(csr, rowptr, as1, ad1, h1b, b1,
                                                     W2, as2w, ad2w, g, as2, ad2, N);
    // layer 2 + epilogue (16-edge chunks)
    gat2_k<<<(N * 64 + 255) / 256, 256, 0, stream>>>(csr, rowptr, as2, ad2, g, b2v, Wlin, blin,
                                                     (float*)d_out, N);
}

// Round 13
// 403.315 us; speedup vs baseline: 2.9525x; 2.9525x over previous
//
#include <hip/hip_runtime.h>
#include <hip/hip_bf16.h>

__device__ __forceinline__ float lrelu02(float v) { return v > 0.f ? v : 0.2f * v; }

// manual bf16 <-> f32 (RNE); finite data only
__device__ __forceinline__ float bf2f(unsigned short u) {
    union { unsigned int i; float f; } v; v.i = ((unsigned int)u) << 16; return v.f;
}
__device__ __forceinline__ unsigned short f2bf(float f) {
    union { float f; unsigned int i; } v; v.f = f;
    unsigned int x = v.i;
    return (unsigned short)((x + 0x7fffu + ((x >> 16) & 1u)) >> 16);
}
// fp16 store helper (RNE)
__device__ __forceinline__ unsigned short f2h(float f) {
    union { _Float16 h; unsigned short u; } v; v.h = (_Float16)f; return v.u;
}

typedef float f32x4 __attribute__((ext_vector_type(4)));
typedef short s16x8 __attribute__((ext_vector_type(8)));

// half2 vector type derived from the builtin itself (r10 compile fix)
using half2v = decltype(__builtin_amdgcn_cvt_pkrtz(0.f, 0.f));

__device__ __forceinline__ half2v u2h2(unsigned int u) {
    union { unsigned int u; half2v h; } v; v.u = u; return v.h;
}
__device__ __forceinline__ unsigned int h22u(half2v h) {
    union { unsigned int u; half2v h; } v; v.h = h; return v.u;
}

// ---------- rank pass ----------
// r12 post-mortem: the cooperative-kernel CSR build regressed 409->1191us (csr_build_k
// 912us, VALUBusy 0.2%): grid.sync() across 1024 blocks / 8 XCDs costs ~150us PER SYNC
// (device-wide rendezvous through non-coherent L2s) vs ~5-10us per kernel-boundary drain.
// REVERTED to the r11 six-dispatch chain (measured-good). Coop sync is only for
// register/LDS-resident cross-phase state, never for launch-overhead removal.
__global__ __launch_bounds__(256) void rank_k(
    const int* __restrict__ ei, int E, int N,
    int* __restrict__ deg, int* __restrict__ rank)
{
    int e = blockIdx.x * 256 + threadIdx.x;
    if (e >= E + N) return;
    int d = (e < E) ? ei[E + e] : (e - E);
    rank[e] = atomicAdd(&deg[d], 1);
}

// ---------- layer-1 dense via MFMA ----------
// (r5: MFMA verified, absmax held; fp16 h1 output for gat1's fdot2 path.)
__global__ __launch_bounds__(512) void gemm1_k(
    const float* __restrict__ x, const float* __restrict__ W1,
    const float* __restrict__ aw_s, const float* __restrict__ aw_d,
    unsigned short* __restrict__ h1b, float* __restrict__ as1, float* __restrict__ ad1, int N)
{
    // --- stage W1 transposed as bf16: Wt[col][k ^ ((col&7)<<3)] ---
    __shared__ unsigned short Wt[128 * 128];   // 32 KB
    {
        const float4* W4 = (const float4*)W1;
        for (int i = threadIdx.x; i < 128 * 32; i += 512) {
            float4 f = W4[i];                      // row k = i>>5, cols 4t..4t+3
            int k = i >> 5, c4 = (i & 31) * 4;
            #pragma unroll
            for (int j = 0; j < 4; ++j) {
                int col = c4 + j;
                float fv = j == 0 ? f.x : j == 1 ? f.y : j == 2 ? f.z : f.w;
                Wt[col * 128 + (k ^ ((col & 7) << 3))] = f2bf(fv);
            }
        }
    }

    const int lane = threadIdx.x & 63;
    const int wv   = threadIdx.x >> 6;          // 0..7
    const int li   = lane & 15;                 // M-row (A) / N-col (B,D) index
    const int kg   = lane >> 4;                 // k-subchunk 0..3
    const int row0 = blockIdx.x * 128 + wv * 16;

    const int rc = (row0 + li < N) ? (row0 + li) : (N - 1);   // clamped A row
    const float4* xr = (const float4*)(x + (size_t)rc * 128);

    f32x4 acc[8];
    #pragma unroll
    for (int ct = 0; ct < 8; ++ct) acc[ct] = {0.f, 0.f, 0.f, 0.f};

    __syncthreads();

    #pragma unroll
    for (int ks = 0; ks < 4; ++ks) {
        // A fragment: x[rc][ks*32 + kg*8 .. +7] as hi/lo bf16 split
        float4 f0 = xr[ks * 8 + kg * 2];
        float4 f1 = xr[ks * 8 + kg * 2 + 1];
        float xf[8] = {f0.x, f0.y, f0.z, f0.w, f1.x, f1.y, f1.z, f1.w};
        s16x8 ahi, alo;
        #pragma unroll
        for (int j = 0; j < 8; ++j) {
            unsigned short h = f2bf(xf[j]);
            ahi[j] = (short)h;
            alo[j] = (short)f2bf(xf[j] - bf2f(h));
        }
        const int kbase = ks * 32 + kg * 8;
        #pragma unroll
        for (int ct = 0; ct < 8; ++ct) {
            const int col = ct * 16 + li;
            const s16x8 b = *reinterpret_cast<const s16x8*>(
                Wt + col * 128 + (kbase ^ ((col & 7) << 3)));
            acc[ct] = __builtin_amdgcn_mfma_f32_16x16x32_bf16(ahi, b, acc[ct], 0, 0, 0);
            acc[ct] = __builtin_amdgcn_mfma_f32_16x16x32_bf16(alo, b, acc[ct], 0, 0, 0);
        }
    }

    // --- epilogue: attn dots + fp16 h1 write ---
    float aws_[8], awd_[8];
    #pragma unroll
    for (int t = 0; t < 8; ++t) { aws_[t] = aw_s[t * 16 + li]; awd_[t] = aw_d[t * 16 + li]; }

    #pragma unroll
    for (int i = 0; i < 4; ++i) {
        const int gr = row0 + (lane >> 4) * 4 + i;
        const bool valid = gr < N;
        float s0 = acc[0][i] * aws_[0] + acc[1][i] * aws_[1];
        float s1 = acc[2][i] * aws_[2] + acc[3][i] * aws_[3];
        float s2 = acc[4][i] * aws_[4] + acc[5][i] * aws_[5];
        float s3 = acc[6][i] * aws_[6] + acc[7][i] * aws_[7];
        float d0 = acc[0][i] * awd_[0] + acc[1][i] * awd_[1];
        float d1 = acc[2][i] * awd_[2] + acc[3][i] * awd_[3];
        float d2 = acc[4][i] * awd_[4] + acc[5][i] * awd_[5];
        float d3 = acc[6][i] * awd_[6] + acc[7][i] * awd_[7];
        #pragma unroll
        for (int m = 1; m < 16; m <<= 1) {
            s0 += __shfl_xor(s0, m, 16); s1 += __shfl_xor(s1, m, 16);
            s2 += __shfl_xor(s2, m, 16); s3 += __shfl_xor(s3, m, 16);
            d0 += __shfl_xor(d0, m, 16); d1 += __shfl_xor(d1, m, 16);
            d2 += __shfl_xor(d2, m, 16); d3 += __shfl_xor(d3, m, 16);
        }
        if (valid) {
            if (li < 4) {
                float sv = li == 0 ? s0 : li == 1 ? s1 : li == 2 ? s2 : s3;
                float dv = li == 0 ? d0 : li == 1 ? d1 : li == 2 ? d2 : d3;
                as1[gr * 4 + li] = sv;
                ad1[gr * 4 + li] = dv;
            }
            #pragma unroll
            for (int ct = 0; ct < 8; ++ct)
                h1b[(size_t)gr * 128 + ct * 16 + li] = f2h(acc[ct][i]);
        }
    }
}

// ---------- CSR scan ----------
__global__ __launch_bounds__(256) void blocksum_k(
    const int* __restrict__ deg, int N, int* __restrict__ bsum)
{
    __shared__ int sh[256];
    int i = blockIdx.x * 256 + threadIdx.x;
    sh[threadIdx.x] = (i < N) ? deg[i] : 0;
    __syncthreads();
    for (int off = 128; off; off >>= 1) {
        if (threadIdx.x < off) sh[threadIdx.x] += sh[threadIdx.x + off];
        __syncthreads();
    }
    if (threadIdx.x == 0) bsum[blockIdx.x] = sh[0];
}

__global__ __launch_bounds__(1024) void scanbsum_k(int* __restrict__ bsum, int nb)
{
    __shared__ int buf[1024];
    __shared__ int carry;
    if (threadIdx.x == 0) carry = 0;
    __syncthreads();
    for (int base = 0; base < nb; base += 1024) {
        int i = base + threadIdx.x;
        int v = (i < nb) ? bsum[i] : 0;
        buf[threadIdx.x] = v;
        __syncthreads();
        for (int off = 1; off < 1024; off <<= 1) {
            int t = (threadIdx.x >= off) ? buf[threadIdx.x - off] : 0;
            __syncthreads();
            buf[threadIdx.x] += t;
            __syncthreads();
        }
        if (i < nb) bsum[i] = buf[threadIdx.x] - v + carry;   // exclusive
        __syncthreads();
        if (threadIdx.x == 0) carry += buf[1023];
        __syncthreads();
    }
}

__global__ __launch_bounds__(256) void rowptr_k(
    const int* __restrict__ deg, const int* __restrict__ bsum, int N, int E,
    int* __restrict__ rowptr)
{
    __shared__ int buf[256];
    int i = blockIdx.x * 256 + threadIdx.x;
    int v = (i < N) ? deg[i] : 0;
    buf[threadIdx.x] = v;
    __syncthreads();
    for (int off = 1; off < 256; off <<= 1) {
        int t = (threadIdx.x >= off) ? buf[threadIdx.x - off] : 0;
        __syncthreads();
        buf[threadIdx.x] += t;
        __syncthreads();
    }
    if (i < N) rowptr[i] = bsum[blockIdx.x] + buf[threadIdx.x] - v;
    if (i == 0) rowptr[N] = E + N;
}

// Pure scatter, no atomic (rank already known).
__global__ __launch_bounds__(256) void place_k(
    const int* __restrict__ ei, int E, int N,
    const int* __restrict__ rank, const int* __restrict__ rowptr,
    int* __restrict__ csr)
{
    int e = blockIdx.x * 256 + threadIdx.x;
    if (e >= E + N) return;
    int s, d;
    if (e < E) { s = ei[e]; d = ei[E + e]; } else { s = d = e - E; }
    csr[rowptr[d] + rank[e]] = s;
}

// ---------- layer-1 fused: softmax-aggregate + bias + ELU + gemm2 + attn2 dots ----------
// (r11: fdot2-pair version verified, 114 -> 92us, absmax held.)
__global__ __launch_bounds__(256) void gat1_k(
    const int* __restrict__ csr, const int* __restrict__ rowptr,
    const float* __restrict__ as1, const float* __restrict__ ad1,
    const unsigned short* __restrict__ h1b, const float* __restrict__ b1,
    const float* __restrict__ W2, const float* __restrict__ aw_s2, const float* __restrict__ aw_d2,
    float* __restrict__ g, float* __restrict__ as2, float* __restrict__ ad2, int N)
{
    __shared__ float red[4][8][12];   // [wave][src-lane][j]
    const int wv   = threadIdx.x >> 6;
    const int wid  = (blockIdx.x * 256 + threadIdx.x) >> 6;
    const int lane = threadIdx.x & 63;
    if (wid >= N) return;
    const int start = rowptr[wid], end = rowptr[wid + 1];
    const int i16 = lane & 15;
    const int hh  = lane >> 4;
    const float adh = ad1[wid * 4 + hh];
    const float mh  = lrelu02(as1[wid * 4 + hh] + adh);   // self-logit offset (den >= 1)
    const unsigned short* hb = h1b + lane * 2;            // this lane's 2 cols (fp16)

    float den = 0.f, acc0 = 0.f, acc1 = 0.f;

    int   s = 0;
    unsigned int wpku = 0;

    auto pair_step = [&](int p) {
        const int se0 = __builtin_amdgcn_readlane(s, 2 * p);
        const int se1 = __builtin_amdgcn_readlane(s, 2 * p + 1);
        const unsigned int wp = (unsigned int)__shfl((int)wpku, 2 * p, 16);
        const unsigned int pv0 = *(const unsigned int*)(hb + (size_t)se0 * 128);
        const unsigned int pv1 = *(const unsigned int*)(hb + (size_t)se1 * 128);
        const unsigned int lo = __builtin_amdgcn_perm(pv1, pv0, 0x05040100u); // (h_e0[c], h_e1[c])
        const unsigned int hi = __builtin_amdgcn_perm(pv1, pv0, 0x07060302u); // (h_e0[c+1], h_e1[c+1])
        acc0 = __builtin_amdgcn_fdot2(u2h2(wp), u2h2(lo), acc0, false);
        acc1 = __builtin_amdgcn_fdot2(u2h2(wp), u2h2(hi), acc1, false);
    };

    int k0 = start;
    int cnt = end - k0; cnt = cnt > 16 ? 16 : cnt;        // first chunk (>=1: self loop)
    s = (i16 < cnt) ? csr[k0 + i16] : wid;
    float w = (i16 < cnt) ? __expf(lrelu02(as1[(size_t)s * 4 + hh] + adh) - mh) : 0.f;

    while (true) {
        // prefetch next chunk's loads before consuming the current one
        const int k1 = k0 + 16;
        int cnt_n = end - k1; cnt_n = cnt_n > 16 ? 16 : cnt_n;   // may be <= 0
        int   s_n = wid;
        float a_n = 0.f;
        if (cnt_n > 0) {
            s_n = (i16 < cnt_n) ? csr[k1 + i16] : wid;
            a_n = as1[(size_t)s_n * 4 + hh];
        }

        den += w;
        // pack (w_i, w_i+1) on even lanes; pairs stay within the 16-lane head group
        const float wn = __shfl_xor(w, 1);
        wpku = h22u(__builtin_amdgcn_cvt_pkrtz(w, wn));

        if (cnt == 16) {
            #pragma unroll
            for (int p = 0; p < 8; ++p) pair_step(p);
        } else {
            const int pairs = (cnt + 1) >> 1;
            for (int p = 0; p < pairs; ++p) pair_step(p);
        }
        if (cnt_n <= 0) break;
        s = s_n;
        w = (i16 < cnt_n) ? __expf(lrelu02(a_n + adh) - mh) : 0.f;
        k0 = k1; cnt = cnt_n;
    }

    den += __shfl_xor(den, 1); den += __shfl_xor(den, 2);
    den += __shfl_xor(den, 4); den += __shfl_xor(den, 8);
    const float rden = 1.f / (den + 1e-16f);
    float v0 = acc0 * rden + b1[lane * 2];
    float v1 = acc1 * rden + b1[lane * 2 + 1];
    v0 = v0 > 0.f ? v0 : expm1f(v0);
    v1 = v1 > 0.f ? v1 : expm1f(v1);

    // --- fused gemm2: g_j = sum_k elu_out[k] * W2[k][j] (k = 2*lane, 2*lane+1) ---
    const float4 a0 = *(const float4*)(W2 + 16 * lane);
    const float4 a1 = *(const float4*)(W2 + 16 * lane + 4);
    const float4 b0 = *(const float4*)(W2 + 16 * lane + 8);
    const float4 b1v = *(const float4*)(W2 + 16 * lane + 12);
    float p[8];
    p[0] = v0 * a0.x + v1 * b0.x;  p[1] = v0 * a0.y + v1 * b0.y;
    p[2] = v0 * a0.z + v1 * b0.z;  p[3] = v0 * a0.w + v1 * b0.w;
    p[4] = v0 * a1.x + v1 * b1v.x; p[5] = v0 * a1.y + v1 * b1v.y;
    p[6] = v0 * a1.z + v1 * b1v.z; p[7] = v0 * a1.w + v1 * b1v.w;
    #pragma unroll
    for (int j = 0; j < 8; ++j) {
        p[j] += __shfl_xor(p[j], 8);
        p[j] += __shfl_xor(p[j], 16);
        p[j] += __shfl_xor(p[j], 32);
    }
    if (lane < 8) {
        #pragma unroll
        for (int j = 0; j < 8; ++j) red[wv][lane][j] = p[j];
    }
    if (lane < 8) {
        float gj = 0.f;
        #pragma unroll
        for (int c = 0; c < 8; ++c) gj += red[wv][c][lane];
        g[(size_t)wid * 8 + lane] = gj;
        float ts = gj * aw_s2[lane], td = gj * aw_d2[lane];
        ts += __shfl_xor(ts, 1); ts += __shfl_xor(ts, 2); ts += __shfl_xor(ts, 4);
        td += __shfl_xor(td, 1); td += __shfl_xor(td, 2); td += __shfl_xor(td, 4);
        if (lane == 0) { as2[wid] = ts; ad2[wid] = td; }
    }
}

// ---------- layer-2 single-pass softmax+aggregate+epilogue: one wave per dst ----------
// 16-edge chunks (kept from r12): halves loop iterations, doubles independent g-gathers
// per iteration. den reduce xor 1/2/4/8; acc reduce xor 8/16/32 across the 8 groups.
__global__ __launch_bounds__(256) void gat2_k(
    const int* __restrict__ csr, const int* __restrict__ rowptr,
    const float* __restrict__ as2, const float* __restrict__ ad2,
    const float* __restrict__ g, const float* __restrict__ b2_,
    const float* __restrict__ Wlin, const float* __restrict__ blin,
    float* __restrict__ out, int N)
{
    const int wid  = (blockIdx.x * 256 + threadIdx.x) >> 6;
    const int lane = threadIdx.x & 63;
    if (wid >= N) return;
    const int start = rowptr[wid], end = rowptr[wid + 1];
    const int i16 = lane & 15;
    const int i8  = lane & 7;
    const int grp = lane >> 3;
    const float adh = ad2[wid];
    const float mh  = lrelu02(as2[wid] + adh);
    float den = 0.f, acc = 0.f;

    int k0 = start;
    int cnt = end - k0; cnt = cnt > 16 ? 16 : cnt;
    int   s = (i16 < cnt) ? csr[k0 + i16] : wid;
    float w = (i16 < cnt) ? __expf(lrelu02(as2[s] + adh) - mh) : 0.f;

    while (true) {
        const int k1 = k0 + 16;
        int cnt_n = end - k1; cnt_n = cnt_n > 16 ? 16 : cnt_n;
        int   s_n = wid;
        float a_n = 0.f;
        if (cnt_n > 0) {
            s_n = (i16 < cnt_n) ? csr[k1 + i16] : wid;
            a_n = as2[s_n];
        }

        den += w;
        const int   se0 = __shfl(s, grp);
        const int   se1 = __shfl(s, grp + 8);
        const float we0 = __shfl(w, grp);
        const float we1 = __shfl(w, grp + 8);
        const float gv0 = g[(size_t)se0 * 8 + i8];
        const float gv1 = g[(size_t)se1 * 8 + i8];
        acc = fmaf(we0, gv0, acc);
        acc = fmaf(we1, gv1, acc);

        if (cnt_n <= 0) break;
        s = s_n;
        w = (i16 < cnt_n) ? __expf(lrelu02(a_n + adh) - mh) : 0.f;
        k0 = k1; cnt = cnt_n;
    }

    den += __shfl_xor(den, 1); den += __shfl_xor(den, 2);
    den += __shfl_xor(den, 4); den += __shfl_xor(den, 8);
    acc += __shfl_xor(acc, 8); acc += __shfl_xor(acc, 16); acc += __shfl_xor(acc, 32);
    float v = acc / (den + 1e-16f) + b2_[i8];
    v = v > 0.f ? v : expm1f(v);
    float t = v * Wlin[i8];
    t += __shfl_xor(t, 1); t += __shfl_xor(t, 2); t += __shfl_xor(t, 4);
    if (lane == 0) out[wid] = 1.f / (1.f + __expf(-(t + blin[0])));
}

extern "C" void kernel_launch(void* const* d_in, const int* in_sizes, int n_in,
                              void* d_out, int out_size, void* d_ws, size_t ws_size,
                              hipStream_t stream)
{
    (void)n_in; (void)out_size; (void)ws_size;
    const float* x    = (const float*)d_in[0];
    const int*   ei   = (const int*)d_in[1];
    // d_in[2] = edge_attr, ignored
    const float* W1   = (const float*)d_in[3];
    const float* as1w = (const float*)d_in[4];
    const float* ad1w = (const float*)d_in[5];
    const float* b1   = (const float*)d_in[6];
    const float* W2   = (const float*)d_in[7];
    const float* as2w = (const float*)d_in[8];
    const float* ad2w = (const float*)d_in[9];
    const float* b2v  = (const float*)d_in[10];
    const float* Wlin = (const float*)d_in[11];
    const float* blin = (const float*)d_in[12];

    const int N = in_sizes[0] / 128;
    const int E = in_sizes[1] / 2;
    const int total = E + N;

    // workspace layout
    float* p = (float*)d_ws;
    unsigned short* h1b = (unsigned short*)p; p += (size_t)N * 64;  // N*128 fp16
    float* as1  = p; p += (size_t)N * 4;
    float* ad1  = p; p += (size_t)N * 4;
    float* g    = p; p += (size_t)N * 8;
    float* as2  = p; p += (size_t)N;
    float* ad2  = p; p += (size_t)N;
    int* deg    = (int*)p; p += (size_t)N;
    int* rowptr = (int*)p; p += (size_t)N + 1;
    int* bsum   = (int*)p; p += ((size_t)N + 255) / 256;
    int* rank   = (int*)p; p += (size_t)total;
    int* csr    = (int*)p; p += (size_t)total;

    const int eb = (total + 255) / 256;
    const int nb = (N + 255) / 256;

    hipMemsetAsync(deg, 0, (size_t)N * sizeof(int), stream);
    // rank pass (atomics)
    rank_k<<<eb, 256, 0, stream>>>(ei, E, N, deg, rank);
    // layer-1 GEMM on the matrix pipe (MFMA bf16 hi/lo split; fp16 h1 output)
    gemm1_k<<<(N + 127) / 128, 512, 0, stream>>>(x, W1, as1w, ad1w, h1b, as1, ad1, N);
    blocksum_k<<<nb, 256, 0, stream>>>(deg, N, bsum);
    scanbsum_k<<<1, 1024, 0, stream>>>(bsum, nb);
    rowptr_k<<<nb, 256, 0, stream>>>(deg, bsum, N, E, rowptr);
    place_k<<<eb, 256, 0, stream>>>(ei, E, N, rank, rowptr, csr);

    // layer 1: softmax + aggregate + bias + ELU + gemm2 + attn2 dots (fdot2 pairs)
    gat1_k<<<(N * 64 + 255) / 256, 256, 0, stream>>>(csr, rowptr, as1, ad1, h1b, b1,
                                                     W2, as2w, ad2w, g, as2, ad2, N);
    // layer 2 + epilogue (16-edge chunks)
    gat2_k<<<(N * 64 + 255) / 256, 256, 0, stream>>>(csr, rowptr, as2, ad2, g, b2v, Wlin, blin,
                                                     (float*)d_out, N);
}